// Round 1
// baseline (2151.939 us; speedup 1.0000x reference)
//
#include <hip/hip_runtime.h>

typedef _Float16 f16;
typedef _Float16 f16x8 __attribute__((ext_vector_type(8)));
typedef _Float16 f16x4 __attribute__((ext_vector_type(4)));
typedef float f32x4 __attribute__((ext_vector_type(4)));

#define MFMA_F16(A, B, C) __builtin_amdgcn_mfma_f32_16x16x32_f16(A, B, C, 0, 0, 0)

#define TM 128
#define TN 128
#define BK 64
#define LSTR 80  // LDS row stride in f16 elems: 64 + 16 pad = 160 B (16B-aligned, 8-bank skew/row)

// Stage a 128x64 f16 tile (row-major, leading dim ldg) into LDS. 256 threads,
// 4 x 16B chunks each. Coalesced 128 B per global row segment.
__device__ __forceinline__ void stage_tile(const f16* __restrict__ g, int ldg,
                                           f16* __restrict__ s) {
    const int t = threadIdx.x;
#pragma unroll
    for (int i = 0; i < 4; ++i) {
        int c = i * 256 + t;          // 0..1023 chunk id
        int row = c >> 3, p = c & 7;  // 128 rows x 8 chunks of 8 f16
        uint4 v = *(const uint4*)(g + (size_t)row * ldg + p * 8);
        *(uint4*)(s + row * LSTR + p * 8) = v;
    }
}

// ---------------- K1: H = silu(X @ W1^T) * (X @ W3^T), f16 out ----------------
__global__ __launch_bounds__(256) void k1_gate(
    const f16* __restrict__ A, int K,
    const f16* __restrict__ W1, const f16* __restrict__ W3,
    f16* __restrict__ Hout)
{
    __shared__ f16 As[TM * LSTR];
    __shared__ f16 B1s[TN * LSTR];
    __shared__ f16 B3s[TN * LSTR];

    const int hb = blockIdx.x;  // hidden col-block (16)
    const int rb = blockIdx.y;  // row-block (128)
    const int wave = threadIdx.x >> 6;
    const int lane = threadIdx.x & 63;
    const int wr = wave >> 1, wc = wave & 1;
    const int ln = lane & 15, lq = lane >> 4;

    f32x4 acc1[4][4] = {};
    f32x4 acc3[4][4] = {};

    const f16* Ab  = A  + (size_t)rb * TM * 2048;  // obs_f16 ld = 2048
    const f16* B1b = W1 + (size_t)hb * TN * K;
    const f16* B3b = W3 + (size_t)hb * TN * K;

    for (int k0 = 0; k0 < K; k0 += BK) {
        __syncthreads();
        stage_tile(Ab + k0, 2048, As);
        stage_tile(B1b + k0, K, B1s);
        stage_tile(B3b + k0, K, B3s);
        __syncthreads();
#pragma unroll
        for (int ks = 0; ks < 2; ++ks) {
            f16x8 af[4], b1f[4], b3f[4];
#pragma unroll
            for (int mi = 0; mi < 4; ++mi)
                af[mi] = *(const f16x8*)(As + (wr * 64 + mi * 16 + ln) * LSTR + ks * 32 + lq * 8);
#pragma unroll
            for (int ni = 0; ni < 4; ++ni) {
                b1f[ni] = *(const f16x8*)(B1s + (wc * 64 + ni * 16 + ln) * LSTR + ks * 32 + lq * 8);
                b3f[ni] = *(const f16x8*)(B3s + (wc * 64 + ni * 16 + ln) * LSTR + ks * 32 + lq * 8);
            }
#pragma unroll
            for (int mi = 0; mi < 4; ++mi)
#pragma unroll
                for (int ni = 0; ni < 4; ++ni) {
                    acc1[mi][ni] = MFMA_F16(af[mi], b1f[ni], acc1[mi][ni]);
                    acc3[mi][ni] = MFMA_F16(af[mi], b3f[ni], acc3[mi][ni]);
                }
        }
    }

    // epilogue: C/D layout col = lane&15, row = (lane>>4)*4 + reg  [m89-verified]
    const int row0 = rb * TM + wr * 64;
    const int col0 = hb * TN + wc * 64;
#pragma unroll
    for (int mi = 0; mi < 4; ++mi)
#pragma unroll
        for (int r = 0; r < 4; ++r) {
            int row = row0 + mi * 16 + lq * 4 + r;
#pragma unroll
            for (int ni = 0; ni < 4; ++ni) {
                float g1 = acc1[mi][ni][r];
                float g3 = acc3[mi][ni][r];
                float h = g1 / (1.f + __expf(-g1)) * g3;  // silu(g1)*g3
                Hout[(size_t)row * 2048 + col0 + ni * 16 + ln] = (f16)h;
            }
        }
}

// ---------------- K2: raw = H @ W2^T (fp32 to d_out) + per-row partial ss ----------------
__global__ __launch_bounds__(256) void k2_out(
    const f16* __restrict__ Hm, const f16* __restrict__ W2,
    float* __restrict__ outp,   // d_out + g*1024, row stride 7168
    float* __restrict__ ssp)    // ss + g*8*16384, layout [cb][b]
{
    __shared__ f16 As[TM * LSTR];
    __shared__ f16 Bs[TN * LSTR];
    __shared__ float ssTile[TM];

    const int cb = blockIdx.x;  // out col-block (8)
    const int rb = blockIdx.y;  // row-block (128)
    const int wave = threadIdx.x >> 6;
    const int lane = threadIdx.x & 63;
    const int wr = wave >> 1, wc = wave & 1;
    const int ln = lane & 15, lq = lane >> 4;

    if (threadIdx.x < TM) ssTile[threadIdx.x] = 0.f;

    f32x4 acc[4][4] = {};

    const f16* Ab = Hm + (size_t)rb * TM * 2048;
    const f16* Bb = W2 + (size_t)cb * TN * 2048;

    for (int k0 = 0; k0 < 2048; k0 += BK) {
        __syncthreads();
        stage_tile(Ab + k0, 2048, As);
        stage_tile(Bb + k0, 2048, Bs);
        __syncthreads();
#pragma unroll
        for (int ks = 0; ks < 2; ++ks) {
            f16x8 af[4], bf[4];
#pragma unroll
            for (int mi = 0; mi < 4; ++mi)
                af[mi] = *(const f16x8*)(As + (wr * 64 + mi * 16 + ln) * LSTR + ks * 32 + lq * 8);
#pragma unroll
            for (int ni = 0; ni < 4; ++ni)
                bf[ni] = *(const f16x8*)(Bs + (wc * 64 + ni * 16 + ln) * LSTR + ks * 32 + lq * 8);
#pragma unroll
            for (int mi = 0; mi < 4; ++mi)
#pragma unroll
                for (int ni = 0; ni < 4; ++ni)
                    acc[mi][ni] = MFMA_F16(af[mi], bf[ni], acc[mi][ni]);
        }
    }

    const int lrow0 = wr * 64;
    const int gcol0 = cb * TN + wc * 64;
#pragma unroll
    for (int mi = 0; mi < 4; ++mi)
#pragma unroll
        for (int r = 0; r < 4; ++r) {
            int lrow = lrow0 + mi * 16 + lq * 4 + r;
            size_t grow = (size_t)(rb * TM + lrow);
            float s = 0.f;
#pragma unroll
            for (int ni = 0; ni < 4; ++ni) {
                float c = acc[mi][ni][r];
                s += c * c;
                outp[grow * 7168 + gcol0 + ni * 16 + ln] = c;
            }
            // 16 lanes (same lq) hold this row's 16 cols of each frag: butterfly over low 4 bits
            s += __shfl_xor(s, 1);
            s += __shfl_xor(s, 2);
            s += __shfl_xor(s, 4);
            s += __shfl_xor(s, 8);
            if (ln == 0) atomicAdd(&ssTile[lrow], s);  // ds_add_f32; waves 0/1 and 2/3 share rows
        }
    __syncthreads();
    if (threadIdx.x < TM)
        ssp[(size_t)cb * 16384 + rb * TM + threadIdx.x] = ssTile[threadIdx.x];
}

// ---------------- K3: in-place RMS norm + affine + term_embed ----------------
__global__ __launch_bounds__(256) void k3_norm(
    float* __restrict__ outp, const float* __restrict__ ss,
    const float* __restrict__ nw, const float* __restrict__ nb,
    const float* __restrict__ te)
{
    const int rrow = blockIdx.x;  // b*7 + g
    const int g = rrow % 7;
    const int b = rrow / 7;
    float ssum = 0.f;
#pragma unroll
    for (int cb = 0; cb < 8; ++cb) ssum += ss[(size_t)(g * 8 + cb) * 16384 + b];
    const float rinv = 1.0f / sqrtf(ssum * (1.0f / 1024.0f) + 1e-5f);
    const int t = threadIdx.x;
    float4* rowp = (float4*)(outp + (size_t)rrow * 1024);
    float4 x = rowp[t];
    float4 w = ((const float4*)nw)[t];
    float4 bb = ((const float4*)nb)[t];
    float4 e = ((const float4*)(te + g * 1024))[t];
    float4 o;
    o.x = x.x * rinv * w.x + bb.x + e.x;
    o.y = x.y * rinv * w.y + bb.y + e.y;
    o.z = x.z * rinv * w.z + bb.z + e.z;
    o.w = x.w * rinv * w.w + bb.w + e.w;
    rowp[t] = o;
}

// ---------------- K0: fp32 -> f16 convert (n multiple of 1024) ----------------
__global__ __launch_bounds__(256) void cvt_f16(const float* __restrict__ s, f16* __restrict__ d) {
    size_t i = (size_t)blockIdx.x * 256 + threadIdx.x;
    float4 v = ((const float4*)s)[i];
    f16x4 o = { (f16)v.x, (f16)v.y, (f16)v.z, (f16)v.w };
    ((f16x4*)d)[i] = o;
}

extern "C" void kernel_launch(void* const* d_in, const int* in_sizes, int n_in,
                              void* d_out, int out_size, void* d_ws, size_t ws_size,
                              hipStream_t stream) {
    const float* obs  = (const float*)d_in[0];
    const float* w1g0 = (const float*)d_in[1];
    const float* w3g0 = (const float*)d_in[2];
    const float* w2g0 = (const float*)d_in[3];
    const float* w1r  = (const float*)d_in[4];
    const float* w3r  = (const float*)d_in[5];
    const float* w2r  = (const float*)d_in[6];
    const float* nw   = (const float*)d_in[7];
    const float* nb   = (const float*)d_in[8];
    const float* te   = (const float*)d_in[9];

    // ws layout (f16 elems): obs 33554432 | w1g0 1048576 | w3g0 1048576 | w2g0 2097152
    //                        | w1r 3145728 | w3r 3145728 | w2r 12582912 | Hbuf 33554432 | ss (f32)
    // total ~184 MB
    f16* obs_h  = (f16*)d_ws;
    f16* w1g0_h = obs_h  + 33554432;
    f16* w3g0_h = w1g0_h + 1048576;
    f16* w2g0_h = w3g0_h + 1048576;
    f16* w1r_h  = w2g0_h + 2097152;
    f16* w3r_h  = w1r_h  + 3145728;
    f16* w2r_h  = w3r_h  + 3145728;
    f16* Hbuf   = w2r_h  + 12582912;
    float* ssb  = (float*)(Hbuf + 33554432);

    cvt_f16<<<33554432 / 1024, 256, 0, stream>>>(obs, obs_h);
    cvt_f16<<<1048576 / 1024, 256, 0, stream>>>(w1g0, w1g0_h);
    cvt_f16<<<1048576 / 1024, 256, 0, stream>>>(w3g0, w3g0_h);
    cvt_f16<<<2097152 / 1024, 256, 0, stream>>>(w2g0, w2g0_h);
    cvt_f16<<<3145728 / 1024, 256, 0, stream>>>(w1r, w1r_h);
    cvt_f16<<<3145728 / 1024, 256, 0, stream>>>(w3r, w3r_h);
    cvt_f16<<<12582912 / 1024, 256, 0, stream>>>(w2r, w2r_h);

    for (int g = 0; g < 7; ++g) {
        const f16* A  = obs_h + (g == 0 ? 0 : 512 + (g - 1) * 256);
        int K         = (g == 0) ? 512 : 256;
        const f16* W1 = (g == 0) ? w1g0_h : w1r_h + (size_t)(g - 1) * 2048 * 256;
        const f16* W3 = (g == 0) ? w3g0_h : w3r_h + (size_t)(g - 1) * 2048 * 256;
        const f16* W2 = (g == 0) ? w2g0_h : w2r_h + (size_t)(g - 1) * 1024 * 2048;
        k1_gate<<<dim3(16, 128), 256, 0, stream>>>(A, K, W1, W3, Hbuf);
        k2_out<<<dim3(8, 128), 256, 0, stream>>>(Hbuf, W2, (float*)d_out + g * 1024,
                                                 ssb + (size_t)g * 8 * 16384);
    }
    k3_norm<<<114688, 256, 0, stream>>>((float*)d_out, ssb, nw, nb, te);
}